// Round 19
// baseline (92.045 us; speedup 1.0000x reference)
//
#include <hip/hip_runtime.h>
#include <hip/hip_fp16.h>

// SpMM scatter-reduce: out[r] = sum_{e: rows[e]==r} vals[e] * embeds[cols[e]]
// Round-17 structure (RPB=128, finalize@512 — measured-best shape) with
// ONE-CACHELINE int8 embed rows and the per-row scale FOLDED INTO the edge
// value at place time (fixes round 11's two regressions: no in-loop scale
// load, no extra VALU in the hot gather loop).
//   1) count_convert @1024 thr: blocks [0,NWG): per-WG LDS histogram over 782
//      buckets -> cnt[b][w]. Blocks [NWG,..): one row per wave: absmax-reduce,
//      int8-quantize into 64 B rows (48 i8 + pad), scale -> scale_h[row].
//   2) scan_phase1 / 3) scan_phase3: 3-phase exclusive scan -> bstart[]
//   4) place_kernel @1024 thr: LDS cursors; .x = localrow<<17|col,
//      .y = fp16(val * scale[col])<<17 | col   (scale folded here).
//   5) finalize_spmm @512 thr: pass1 count, 2-wave shfl scan, pass2 scatter
//      .y into row-sorted LDS, then row-parallel int8 spmm: one ushort (2xi8)
//      load per edge-lane -> 2 cvt + 2 fma. Gather = exactly 1 cacheline.

#define N_NODES 100000
#define N_EDGES 1600000
#define D_FEAT  48

#define RPB 128
#define NBUCKETS ((N_NODES + RPB - 1) / RPB)                    // 782
#define NWG 256
#define CHUNK ((N_EDGES + NWG - 1) / NWG)                       // 6250
#define MAT (NBUCKETS * NWG)                                    // 200192
#define SCAN_CHUNK 1024
#define NB_SCAN ((MAT + SCAN_CHUNK - 1) / SCAN_CHUNK)           // 196
#define QROWS_PER_BLK 16
#define QBLK (N_NODES / QROWS_PER_BLK)                          // 6250
#define CAP 3072   // bucket mean 2048, sd ~45 -> ~23 sigma headroom

// ---- 1) fused: per-WG bucket histogram + int8 row quantizer (1024 thr) ----
__global__ __launch_bounds__(1024) void count_convert(const int* __restrict__ rows,
                                                      unsigned int* __restrict__ mat,
                                                      const float2* __restrict__ esrc,
                                                      unsigned short* __restrict__ embq,
                                                      __half* __restrict__ scale_h) {
    const int t = threadIdx.x;
    if (blockIdx.x < NWG) {
        __shared__ unsigned int lc[NBUCKETS];
        const int w = blockIdx.x;
        for (int i = t; i < NBUCKETS; i += 1024) lc[i] = 0u;
        __syncthreads();
        const int lo = w * CHUNK;
        const int hi = (lo + CHUNK < N_EDGES) ? lo + CHUNK : N_EDGES;
        for (int e = lo + t; e < hi; e += 1024)
            atomicAdd(&lc[((unsigned)rows[e]) >> 7], 1u);
        __syncthreads();
        for (int b = t; b < NBUCKETS; b += 1024)
            mat[b * NWG + w] = lc[b];
    } else {
        // one embed row per 64-lane wave; lanes 0..23 hold float2 (2 feats)
        const int row  = (blockIdx.x - NWG) * QROWS_PER_BLK + (t >> 6);
        const int lane = t & 63;
        if (row < N_NODES) {
            float2 v = make_float2(0.f, 0.f);
            if (lane < 24) v = esrc[(size_t)row * 24 + lane];
            float m = fmaxf(fabsf(v.x), fabsf(v.y));
#pragma unroll
            for (int mask = 1; mask <= 32; mask <<= 1)
                m = fmaxf(m, __shfl_xor(m, mask));
            float inv = (m > 0.f) ? 127.f / m : 0.f;
            if (lane < 24) {
                int lo8 = __float2int_rn(v.x * inv);
                int hi8 = __float2int_rn(v.y * inv);
                embq[(size_t)row * 32 + lane] =
                    (unsigned short)((lo8 & 0xff) | ((hi8 & 0xff) << 8));
            }
            if (lane == 24)
                scale_h[row] = __float2half(m * (1.f / 127.f));
        }
    }
}

// ---- 2) per-block sums ----
__global__ __launch_bounds__(256) void scan_phase1(const unsigned int* __restrict__ mat,
                                                   unsigned int* __restrict__ bsum) {
    __shared__ unsigned int s[256];
    const int blk = blockIdx.x, t = threadIdx.x;
    const int base = blk * SCAN_CHUNK + t * 4;
    unsigned int sum = 0;
#pragma unroll
    for (int k = 0; k < 4; ++k) {
        int i = base + k;
        if (i < MAT) sum += mat[i];
    }
    s[t] = sum;
    __syncthreads();
    for (int off = 128; off > 0; off >>= 1) {
        if (t < off) s[t] += s[t + off];
        __syncthreads();
    }
    if (t == 0) bsum[blk] = s[0];
}

// ---- 3) apply (each block rescans all 196 block sums locally) ----
__global__ __launch_bounds__(256) void scan_phase3(unsigned int* __restrict__ mat,
                                                   const unsigned int* __restrict__ bsum,
                                                   unsigned int* __restrict__ bstart) {
    __shared__ unsigned int s[256];
    __shared__ unsigned int bpre[256];
    const int blk = blockIdx.x, t = threadIdx.x;
    bpre[t] = (t < NB_SCAN) ? bsum[t] : 0u;
    __syncthreads();
    for (int off = 1; off < 256; off <<= 1) {
        unsigned int u = (t >= off) ? bpre[t - off] : 0u;
        __syncthreads();
        bpre[t] += u;
        __syncthreads();
    }
    const unsigned int blkbase = (blk == 0) ? 0u : bpre[blk - 1];

    const int base = blk * SCAN_CHUNK + t * 4;
    unsigned int c[4];
    unsigned int sum = 0;
#pragma unroll
    for (int k = 0; k < 4; ++k) {
        int i = base + k;
        c[k] = (i < MAT) ? mat[i] : 0u;
        sum += c[k];
    }
    s[t] = sum;
    __syncthreads();
    for (int off = 1; off < 256; off <<= 1) {
        unsigned int u = (t >= off) ? s[t - off] : 0u;
        __syncthreads();
        s[t] += u;
        __syncthreads();
    }
    unsigned int prefix = blkbase + ((t == 0) ? 0u : s[t - 1]);
#pragma unroll
    for (int k = 0; k < 4; ++k) {
        int i = base + k;
        if (i < MAT) {
            mat[i] = prefix;
            if ((i & (NWG - 1)) == 0) bstart[i >> 8] = prefix;
            prefix += c[k];
        }
    }
    if (blk == 0 && t == 0) bstart[NBUCKETS] = N_EDGES;
}

// ---- 4) placement (1024 thr): scale folded into edge value here ----
__global__ __launch_bounds__(1024) void place_kernel(const int* __restrict__ rows,
                                                     const int* __restrict__ cols,
                                                     const float* __restrict__ vals,
                                                     const __half* __restrict__ scale_h,
                                                     const unsigned int* __restrict__ mat,
                                                     int2* __restrict__ buf1) {
    __shared__ unsigned int lc[NBUCKETS];
    const int w = blockIdx.x, t = threadIdx.x;
    for (int b = t; b < NBUCKETS; b += 1024) lc[b] = mat[b * NWG + w];
    __syncthreads();
    const int lo = w * CHUNK;
    const int hi = (lo + CHUNK < N_EDGES) ? lo + CHUNK : N_EDGES;
    for (int e = lo + t; e < hi; e += 1024) {
        unsigned r = (unsigned)rows[e];
        unsigned c = (unsigned)cols[e];
        unsigned int pos = atomicAdd(&lc[r >> 7], 1u);   // LDS atomic only
        // vs = val * scale[col] >= 0 -> fp16 RN bits fit in 15 bits (sign 0)
        float vs = vals[e] * __half2float(scale_h[c]);
        unsigned hv = (unsigned)__half_as_ushort(__float2half_rn(vs));
        buf1[pos] = make_int2((int)(((r & 127u) << 17) | c),
                              (int)((hv << 17) | c));
    }
}

// ---- 5) fused per-bucket counting-sort (LDS) + row-parallel int8 spmm ----
__global__ __launch_bounds__(512) void finalize_spmm(const unsigned int* __restrict__ bstart,
                                                     const int2* __restrict__ buf1,
                                                     const unsigned short* __restrict__ embq,
                                                     float* __restrict__ out) {
    __shared__ unsigned int sedge[CAP];          // (fp16 vs << 17)|col, row-sorted
    __shared__ unsigned int rstart[RPB + 1];
    __shared__ unsigned int rc[RPB];
    __shared__ unsigned int wtot[2];
    const int b = blockIdx.x, t = threadIdx.x;
    const unsigned int S = bstart[b];
    const unsigned int E = bstart[b + 1];
    const unsigned int cnt = E - S;
    const int g   = t >> 5;        // 0..15: 16 groups, 8 rows each
    const int sub = t & 31;        // feature pair; active sub < 24
    const bool act = sub < 24;
    const int row0 = b * RPB;

#define PROC(q)                                                          \
    {                                                                    \
        unsigned short qq = embq[(((q) & 0x1FFFFu) << 5) + sub];         \
        float vs = __half2float(__ushort_as_half((unsigned short)((q) >> 17))); \
        ax = fmaf(vs, (float)(int)(signed char)(qq & 0xff), ax);         \
        ay = fmaf(vs, (float)(int)(signed char)(qq >> 8), ay);           \
    }

    if (t < RPB) rc[t] = 0u;
    __syncthreads();
    // pass 1: count rows (cv.x)
    for (unsigned int k = S + t; k < E; k += 512)
        atomicAdd(&rc[(unsigned)buf1[k].x >> 17], 1u);
    __syncthreads();
    // 2-wave shfl inclusive scan over 128 counts
    unsigned int myc = 0, inc = 0;
    if (t < RPB) {
        myc = rc[t];
        inc = myc;
#pragma unroll
        for (int off = 1; off < 64; off <<= 1) {
            unsigned int u = __shfl_up(inc, off, 64);
            if ((t & 63) >= off) inc += u;
        }
        if ((t & 63) == 63) wtot[t >> 6] = inc;
    }
    __syncthreads();
    if (t < RPB) {
        if (t >= 64) inc += wtot[0];
        unsigned int pre = inc - myc;
        rstart[t] = pre;
        rc[t] = pre;                       // reuse as scatter cursor
    }
    if (t == 0) rstart[RPB] = cnt;
    __syncthreads();

    if (cnt <= CAP) {
        // pass 2: scatter pre-packed word into row-sorted LDS
        for (unsigned int k = S + t; k < E; k += 512) {
            int2 cv = buf1[k];
            unsigned int pos = atomicAdd(&rc[(unsigned)cv.x >> 17], 1u);
            sedge[pos] = (unsigned int)cv.y;
        }
        __syncthreads();

        for (int rr = g * 8; rr < g * 8 + 8; ++rr) {
            int row = row0 + rr;
            if (row >= N_NODES) break;
            unsigned int j = rstart[rr], end = rstart[rr + 1];
            float ax = 0.f, ay = 0.f;
            for (; j + 8 <= end; j += 8) {
                unsigned int q0 = sedge[j + 0];
                unsigned int q1 = sedge[j + 1];
                unsigned int q2 = sedge[j + 2];
                unsigned int q3 = sedge[j + 3];
                unsigned int q4 = sedge[j + 4];
                unsigned int q5 = sedge[j + 5];
                unsigned int q6 = sedge[j + 6];
                unsigned int q7 = sedge[j + 7];
                if (act) {
                    PROC(q0) PROC(q1) PROC(q2) PROC(q3)
                    PROC(q4) PROC(q5) PROC(q6) PROC(q7)
                }
            }
            for (; j < end; ++j) {
                unsigned int q = sedge[j];
                if (act) PROC(q)
            }
            if (act)
                *(float2*)(out + (size_t)row * D_FEAT + sub * 2) = make_float2(ax, ay);
        }
    } else {
        // capacity-overflow fallback (~23-sigma event): filter-scan the window
        for (int rr = g * 8; rr < g * 8 + 8; ++rr) {
            int row = row0 + rr;
            if (row >= N_NODES) break;
            float ax = 0.f, ay = 0.f;
            for (unsigned int k = S; k < E; ++k) {
                int2 cv = buf1[k];
                if (((unsigned)cv.x >> 17) == (unsigned)rr && act) {
                    unsigned int q = (unsigned int)cv.y;
                    PROC(q)
                }
            }
            if (act)
                *(float2*)(out + (size_t)row * D_FEAT + sub * 2) = make_float2(ax, ay);
        }
    }
#undef PROC
}

// ---- fallback (tiny ws): edge-parallel global atomics ----
__global__ __launch_bounds__(256) void zero_out_kernel(float4* __restrict__ out, int n4) {
    int i = blockIdx.x * 256 + threadIdx.x;
    if (i < n4) out[i] = make_float4(0.f, 0.f, 0.f, 0.f);
}
__global__ __launch_bounds__(256) void spmm_atomic_kernel(const int* __restrict__ rows,
                                                          const int* __restrict__ cols,
                                                          const float* __restrict__ vals,
                                                          const float* __restrict__ embeds,
                                                          float* __restrict__ out) {
    long long tid = (long long)blockIdx.x * 256 + threadIdx.x;
    const long long total = (long long)N_EDGES * 12;
    if (tid >= total) return;
    int e = (int)(tid / 12), q = (int)(tid % 12);
    int r = rows[e], c = cols[e];
    float v = vals[e];
    const float4 emb = *(const float4*)(embeds + (long long)c * D_FEAT + q * 4);
    float* o = out + (long long)r * D_FEAT + q * 4;
    atomicAdd(o + 0, v * emb.x);
    atomicAdd(o + 1, v * emb.y);
    atomicAdd(o + 2, v * emb.z);
    atomicAdd(o + 3, v * emb.w);
}

extern "C" void kernel_launch(void* const* d_in, const int* in_sizes, int n_in,
                              void* d_out, int out_size, void* d_ws, size_t ws_size,
                              hipStream_t stream) {
    const int*   rows   = (const int*)d_in[0];
    const int*   cols   = (const int*)d_in[1];
    const float* vals   = (const float*)d_in[2];
    const float* embeds = (const float*)d_in[3];
    float*       out    = (float*)d_out;

    // workspace layout (~20.5 MB):
    //   mat: MAT u32 | bstart: NBUCKETS+1 | bsum: NB_SCAN | buf1: E int2 |
    //   embq: N * 64 B (int8 rows) | scale_h: N fp16
    unsigned int* mat = (unsigned int*)d_ws;
    size_t mat_bytes  = ((size_t)MAT * 4 + 15) & ~(size_t)15;
    unsigned int* bstart = (unsigned int*)((char*)d_ws + mat_bytes);
    size_t bs_bytes   = (((size_t)(NBUCKETS + 1) * 4) + 15) & ~(size_t)15;
    unsigned int* bsum = (unsigned int*)((char*)d_ws + mat_bytes + bs_bytes);
    size_t bsum_bytes = (((size_t)NB_SCAN * 4) + 15) & ~(size_t)15;
    int2* buf1 = (int2*)((char*)d_ws + mat_bytes + bs_bytes + bsum_bytes);
    size_t buf1_bytes = (size_t)N_EDGES * 8;
    unsigned short* embq = (unsigned short*)((char*)buf1 + buf1_bytes);
    size_t embq_bytes = (size_t)N_NODES * 64;
    __half* scale_h = (__half*)((char*)embq + embq_bytes);
    size_t need = mat_bytes + bs_bytes + bsum_bytes + buf1_bytes + embq_bytes +
                  (size_t)N_NODES * 2;

    if (ws_size < need) {
        int n4 = out_size / 4;
        zero_out_kernel<<<(n4 + 255) / 256, 256, 0, stream>>>((float4*)out, n4);
        long long total = (long long)N_EDGES * 12;
        spmm_atomic_kernel<<<(int)((total + 255) / 256), 256, 0, stream>>>(rows, cols, vals, embeds, out);
        return;
    }

    count_convert<<<NWG + QBLK, 1024, 0, stream>>>(rows, mat, (const float2*)embeds,
                                                   embq, scale_h);
    scan_phase1<<<NB_SCAN, 256, 0, stream>>>(mat, bsum);
    scan_phase3<<<NB_SCAN, 256, 0, stream>>>(mat, bsum, bstart);
    place_kernel<<<NWG, 1024, 0, stream>>>(rows, cols, vals, scale_h, mat, buf1);
    finalize_spmm<<<NBUCKETS, 512, 0, stream>>>(bstart, buf1, embq, out);
}

// Round 20
// 81.793 us; speedup vs baseline: 1.1254x; 1.1254x over previous
//
#include <hip/hip_runtime.h>
#include <hip/hip_fp16.h>

// SpMM scatter-reduce: out[r] = sum_{e: rows[e]==r} vals[e] * embeds[cols[e]]
// Pipeline (memset + 3 kernels, global scan ELIMINATED via atomic reservation):
//   0) hipMemsetAsync: btot[782] = 0
//   1) count_convert @1024 thr: blocks [0,NWG): per-WG LDS histogram over 782
//      buckets (128 rows); for each nonzero bucket, ONE atomicAdd(&btot[b],cnt)
//      reserves the chunk's contiguous run; returned offset -> mat[b][w].
//      Blocks [NWG,..): embeds fp32 -> fp16.
//   2) place_kernel @1024 thr: prelude = LDS scan of btot[782] -> bstart
//      (per-WG redundant, WG0 publishes); cursors = bstart[b]+mat[b][w];
//      scatter int2: .x = localrow<<17|col, .y = fp16(val)<<17|col.
//   3) finalize_spmm @512 thr, one WG per bucket  [byte-identical to round 17's
//      measured 44.4us form]: pass1 count rows, 2-wave shfl scan, pass2 scatter
//      .y into row-sorted LDS, row-parallel fp16 spmm (16 grp x 32 ln, x8 ILP).

#define N_NODES 100000
#define N_EDGES 1600000
#define D_FEAT  48

#define RPB 128
#define NBUCKETS ((N_NODES + RPB - 1) / RPB)                    // 782
#define NWG 256
#define CHUNK ((N_EDGES + NWG - 1) / NWG)                       // 6250
#define CONV_N4 ((N_NODES * D_FEAT) / 4)                        // 1200000
#define CONV_BLK ((CONV_N4 + 1023) / 1024)                      // 1172
#define CAP 3072   // bucket mean 2048, sd ~45 -> ~23 sigma headroom

// ---- 1) fused: histogram + atomic reservation + fp32->fp16 convert ----
__global__ __launch_bounds__(1024) void count_convert(const int* __restrict__ rows,
                                                      unsigned int* __restrict__ mat,
                                                      unsigned int* __restrict__ btot,
                                                      const float4* __restrict__ esrc,
                                                      __half2* __restrict__ edst) {
    const int t = threadIdx.x;
    if (blockIdx.x < NWG) {
        __shared__ unsigned int lc[NBUCKETS];
        const int w = blockIdx.x;
        for (int i = t; i < NBUCKETS; i += 1024) lc[i] = 0u;
        __syncthreads();
        const int lo = w * CHUNK;
        const int hi = (lo + CHUNK < N_EDGES) ? lo + CHUNK : N_EDGES;
        for (int e = lo + t; e < hi; e += 1024)
            atomicAdd(&lc[((unsigned)rows[e]) >> 7], 1u);
        __syncthreads();
        // reserve this chunk's contiguous run inside each bucket's region
        for (int b = t; b < NBUCKETS; b += 1024) {
            unsigned int c = lc[b];
            if (c) mat[(size_t)b * NWG + w] = atomicAdd(&btot[b], c);
        }
    } else {
        int i = (blockIdx.x - NWG) * 1024 + t;
        if (i < CONV_N4) {
            float4 v = esrc[i];
            edst[2 * i]     = __floats2half2_rn(v.x, v.y);
            edst[2 * i + 1] = __floats2half2_rn(v.z, v.w);
        }
    }
}

// ---- 2) placement (1024 thr): local btot-scan -> bstart; scatter ----
__global__ __launch_bounds__(1024) void place_kernel(const int* __restrict__ rows,
                                                     const int* __restrict__ cols,
                                                     const float* __restrict__ vals,
                                                     const unsigned int* __restrict__ mat,
                                                     const unsigned int* __restrict__ btot,
                                                     unsigned int* __restrict__ bstart,
                                                     int2* __restrict__ buf1) {
    __shared__ unsigned int lc[NBUCKETS];    // cursors
    __shared__ unsigned int sc[1024];        // scan scratch
    const int w = blockIdx.x, t = threadIdx.x;
    // inclusive Hillis-Steele over 782 bucket totals (1024 threads)
    unsigned int v = (t < NBUCKETS) ? btot[t] : 0u;
    sc[t] = v;
    __syncthreads();
    for (int off = 1; off < 1024; off <<= 1) {
        unsigned int u = (t >= off) ? sc[t - off] : 0u;
        __syncthreads();
        sc[t] += u;
        __syncthreads();
    }
    unsigned int pre = (t == 0) ? 0u : sc[t - 1];   // exclusive prefix
    if (t < NBUCKETS) {
        lc[t] = pre + mat[(size_t)t * NWG + w];     // cursor (garbage if empty: unused)
        if (w == 0) bstart[t] = pre;
    }
    if (w == 0 && t == 0) bstart[NBUCKETS] = N_EDGES;
    __syncthreads();

    const int lo = w * CHUNK;
    const int hi = (lo + CHUNK < N_EDGES) ? lo + CHUNK : N_EDGES;
    for (int e = lo + t; e < hi; e += 1024) {
        unsigned r = (unsigned)rows[e];
        unsigned c = (unsigned)cols[e];
        unsigned int pos = atomicAdd(&lc[r >> 7], 1u);   // LDS atomic only
        // val >= 0 -> fp16 RN bits fit in 15 bits (sign 0)
        unsigned hv = (unsigned)__half_as_ushort(__float2half_rn(vals[e]));
        // .x: bits[23:17] = local row (r & 127), bits[16:0] = col (< 2^17)
        // .y: final packed edge word (fp16val<<17)|col
        buf1[pos] = make_int2((int)(((r & 127u) << 17) | c),
                              (int)((hv << 17) | c));
    }
}

// ---- 3) fused per-bucket counting-sort (LDS) + row-parallel fp16 spmm ----
__global__ __launch_bounds__(512) void finalize_spmm(const unsigned int* __restrict__ bstart,
                                                     const int2* __restrict__ buf1,
                                                     const __half2* __restrict__ embeds_h2,
                                                     float* __restrict__ out) {
    __shared__ unsigned int sedge[CAP];          // (fp16val<<17)|col, row-sorted
    __shared__ unsigned int rstart[RPB + 1];
    __shared__ unsigned int rc[RPB];
    __shared__ unsigned int wtot[2];
    const int b = blockIdx.x, t = threadIdx.x;
    const unsigned int S = bstart[b];
    const unsigned int E = bstart[b + 1];
    const unsigned int cnt = E - S;
    const int g   = t >> 5;        // 0..15: 16 groups, 8 rows each
    const int sub = t & 31;        // feature pair; active sub < 24
    const bool act = sub < 24;
    const int row0 = b * RPB;

#define PROC(q)                                                       \
    {                                                                 \
        union { __half h; unsigned short u; } hv;                     \
        hv.u = (unsigned short)((q) >> 17);                           \
        float vv = __half2float(hv.h);                                \
        __half2 e2v = embeds_h2[((q) & 0x1FFFFu) * 24 + sub];         \
        ax = fmaf(vv, __low2float(e2v), ax);                          \
        ay = fmaf(vv, __high2float(e2v), ay);                         \
    }

    if (t < RPB) rc[t] = 0u;
    __syncthreads();
    // pass 1: count rows (cv.x)
    for (unsigned int k = S + t; k < E; k += 512)
        atomicAdd(&rc[(unsigned)buf1[k].x >> 17], 1u);
    __syncthreads();
    // 2-wave shfl inclusive scan over 128 counts
    unsigned int myc = 0, inc = 0;
    if (t < RPB) {
        myc = rc[t];
        inc = myc;
#pragma unroll
        for (int off = 1; off < 64; off <<= 1) {
            unsigned int u = __shfl_up(inc, off, 64);
            if ((t & 63) >= off) inc += u;
        }
        if ((t & 63) == 63) wtot[t >> 6] = inc;
    }
    __syncthreads();
    if (t < RPB) {
        if (t >= 64) inc += wtot[0];
        unsigned int pre = inc - myc;
        rstart[t] = pre;
        rc[t] = pre;                       // reuse as scatter cursor
    }
    if (t == 0) rstart[RPB] = cnt;
    __syncthreads();

    if (cnt <= CAP) {
        // pass 2: scatter pre-packed word into row-sorted LDS
        for (unsigned int k = S + t; k < E; k += 512) {
            int2 cv = buf1[k];
            unsigned int pos = atomicAdd(&rc[(unsigned)cv.x >> 17], 1u);
            sedge[pos] = (unsigned int)cv.y;
        }
        __syncthreads();

        for (int rr = g * 8; rr < g * 8 + 8; ++rr) {
            int row = row0 + rr;
            if (row >= N_NODES) break;
            unsigned int j = rstart[rr], end = rstart[rr + 1];
            float ax = 0.f, ay = 0.f;
            for (; j + 8 <= end; j += 8) {
                unsigned int q0 = sedge[j + 0];
                unsigned int q1 = sedge[j + 1];
                unsigned int q2 = sedge[j + 2];
                unsigned int q3 = sedge[j + 3];
                unsigned int q4 = sedge[j + 4];
                unsigned int q5 = sedge[j + 5];
                unsigned int q6 = sedge[j + 6];
                unsigned int q7 = sedge[j + 7];
                if (act) {
                    PROC(q0) PROC(q1) PROC(q2) PROC(q3)
                    PROC(q4) PROC(q5) PROC(q6) PROC(q7)
                }
            }
            for (; j < end; ++j) {
                unsigned int q = sedge[j];
                if (act) PROC(q)
            }
            if (act)
                *(float2*)(out + (size_t)row * D_FEAT + sub * 2) = make_float2(ax, ay);
        }
    } else {
        // capacity-overflow fallback (~23-sigma event): filter-scan the window
        for (int rr = g * 8; rr < g * 8 + 8; ++rr) {
            int row = row0 + rr;
            if (row >= N_NODES) break;
            float ax = 0.f, ay = 0.f;
            for (unsigned int k = S; k < E; ++k) {
                int2 cv = buf1[k];
                if (((unsigned)cv.x >> 17) == (unsigned)rr && act) {
                    unsigned int q = (unsigned int)cv.y;
                    PROC(q)
                }
            }
            if (act)
                *(float2*)(out + (size_t)row * D_FEAT + sub * 2) = make_float2(ax, ay);
        }
    }
#undef PROC
}

// ---- fallback (tiny ws): edge-parallel global atomics ----
__global__ __launch_bounds__(256) void zero_out_kernel(float4* __restrict__ out, int n4) {
    int i = blockIdx.x * 256 + threadIdx.x;
    if (i < n4) out[i] = make_float4(0.f, 0.f, 0.f, 0.f);
}
__global__ __launch_bounds__(256) void spmm_atomic_kernel(const int* __restrict__ rows,
                                                          const int* __restrict__ cols,
                                                          const float* __restrict__ vals,
                                                          const float* __restrict__ embeds,
                                                          float* __restrict__ out) {
    long long tid = (long long)blockIdx.x * 256 + threadIdx.x;
    const long long total = (long long)N_EDGES * 12;
    if (tid >= total) return;
    int e = (int)(tid / 12), q = (int)(tid % 12);
    int r = rows[e], c = cols[e];
    float v = vals[e];
    const float4 emb = *(const float4*)(embeds + (long long)c * D_FEAT + q * 4);
    float* o = out + (long long)r * D_FEAT + q * 4;
    atomicAdd(o + 0, v * emb.x);
    atomicAdd(o + 1, v * emb.y);
    atomicAdd(o + 2, v * emb.z);
    atomicAdd(o + 3, v * emb.w);
}

extern "C" void kernel_launch(void* const* d_in, const int* in_sizes, int n_in,
                              void* d_out, int out_size, void* d_ws, size_t ws_size,
                              hipStream_t stream) {
    const int*   rows   = (const int*)d_in[0];
    const int*   cols   = (const int*)d_in[1];
    const float* vals   = (const float*)d_in[2];
    const float* embeds = (const float*)d_in[3];
    float*       out    = (float*)d_out;

    // workspace layout (~23.3 MB):
    //   mat: NBUCKETS*NWG u32 (within-bucket run offsets) | btot: NBUCKETS |
    //   bstart: NBUCKETS+1 | buf1: E int2 | embeds_h: N*48 fp16
    unsigned int* mat = (unsigned int*)d_ws;
    size_t mat_bytes  = ((size_t)NBUCKETS * NWG * 4 + 15) & ~(size_t)15;
    unsigned int* btot = (unsigned int*)((char*)d_ws + mat_bytes);
    size_t btot_bytes = (((size_t)NBUCKETS * 4) + 15) & ~(size_t)15;
    unsigned int* bstart = (unsigned int*)((char*)btot + btot_bytes);
    size_t bs_bytes   = (((size_t)(NBUCKETS + 1) * 4) + 15) & ~(size_t)15;
    int2* buf1 = (int2*)((char*)bstart + bs_bytes);
    __half2* embeds_h2 = (__half2*)((char*)buf1 + (size_t)N_EDGES * 8);
    size_t need = mat_bytes + btot_bytes + bs_bytes +
                  (size_t)N_EDGES * 8 + (size_t)N_NODES * D_FEAT * 2;

    if (ws_size < need) {
        int n4 = out_size / 4;
        zero_out_kernel<<<(n4 + 255) / 256, 256, 0, stream>>>((float4*)out, n4);
        long long total = (long long)N_EDGES * 12;
        spmm_atomic_kernel<<<(int)((total + 255) / 256), 256, 0, stream>>>(rows, cols, vals, embeds, out);
        return;
    }

    hipMemsetAsync(btot, 0, (size_t)NBUCKETS * 4, stream);
    count_convert<<<NWG + CONV_BLK, 1024, 0, stream>>>(rows, mat, btot,
                                                       (const float4*)embeds, embeds_h2);
    place_kernel<<<NWG, 1024, 0, stream>>>(rows, cols, vals, mat, btot, bstart, buf1);
    finalize_spmm<<<NBUCKETS, 512, 0, stream>>>(bstart, buf1, embeds_h2, out);
}

// Round 21
// 77.776 us; speedup vs baseline: 1.1835x; 1.0516x over previous
//
#include <hip/hip_runtime.h>
#include <hip/hip_fp16.h>

// SpMM scatter-reduce: out[r] = sum_{e: rows[e]==r} vals[e] * embeds[cols[e]]
// Round-17 pipeline (measured best, 78.5us) with ONE change: finalize merges
// its two staging passes via register caching (each thread caches its <=6
// window elements in named registers during counting; scatters after scan).
//   1) count_convert @1024 thr: blocks [0,NWG): per-WG LDS histogram over 782
//      buckets (128 rows) -> cnt[b][w]. Blocks [NWG,..): embeds fp32 -> fp16.
//   2) scan_phase1: per-block sums of 1024-entry chunks of mat
//   3) scan_phase3: apply (rescans the 196 block sums in LDS); emits bstart[]
//   4) place_kernel @1024 thr: LDS cursors; int2: .x = localrow<<17|col,
//      .y = fp16(val)<<17|col.
//   5) finalize_spmm @512 thr, one WG per bucket: single global read of the
//      window (registers cached), count rows, 2-wave shfl scan, scatter .y
//      from registers into row-sorted LDS, row-parallel fp16 spmm
//      (16 groups x 32 lanes, 8 rows/group, lane = half2 feat pair, x8 ILP).

#define N_NODES 100000
#define N_EDGES 1600000
#define D_FEAT  48

#define RPB 128
#define NBUCKETS ((N_NODES + RPB - 1) / RPB)                    // 782
#define NWG 256
#define CHUNK ((N_EDGES + NWG - 1) / NWG)                       // 6250
#define MAT (NBUCKETS * NWG)                                    // 200192
#define SCAN_CHUNK 1024
#define NB_SCAN ((MAT + SCAN_CHUNK - 1) / SCAN_CHUNK)           // 196
#define CONV_N4 ((N_NODES * D_FEAT) / 4)                        // 1200000
#define CONV_BLK ((CONV_N4 + 1023) / 1024)                      // 1172
#define CAP 3072   // bucket mean 2048, sd ~45 -> ~23 sigma; CAP/512 = 6 regs

// ---- 1) fused: per-WG bucket histogram + embeds fp32 -> fp16 (1024 thr) ----
__global__ __launch_bounds__(1024) void count_convert(const int* __restrict__ rows,
                                                      unsigned int* __restrict__ mat,
                                                      const float4* __restrict__ esrc,
                                                      __half2* __restrict__ edst) {
    const int t = threadIdx.x;
    if (blockIdx.x < NWG) {
        __shared__ unsigned int lc[NBUCKETS];
        const int w = blockIdx.x;
        for (int i = t; i < NBUCKETS; i += 1024) lc[i] = 0u;
        __syncthreads();
        const int lo = w * CHUNK;
        const int hi = (lo + CHUNK < N_EDGES) ? lo + CHUNK : N_EDGES;
        for (int e = lo + t; e < hi; e += 1024)
            atomicAdd(&lc[((unsigned)rows[e]) >> 7], 1u);
        __syncthreads();
        for (int b = t; b < NBUCKETS; b += 1024)
            mat[b * NWG + w] = lc[b];
    } else {
        int i = (blockIdx.x - NWG) * 1024 + t;
        if (i < CONV_N4) {
            float4 v = esrc[i];
            edst[2 * i]     = __floats2half2_rn(v.x, v.y);
            edst[2 * i + 1] = __floats2half2_rn(v.z, v.w);
        }
    }
}

// ---- 2) per-block sums ----
__global__ __launch_bounds__(256) void scan_phase1(const unsigned int* __restrict__ mat,
                                                   unsigned int* __restrict__ bsum) {
    __shared__ unsigned int s[256];
    const int blk = blockIdx.x, t = threadIdx.x;
    const int base = blk * SCAN_CHUNK + t * 4;
    unsigned int sum = 0;
#pragma unroll
    for (int k = 0; k < 4; ++k) {
        int i = base + k;
        if (i < MAT) sum += mat[i];
    }
    s[t] = sum;
    __syncthreads();
    for (int off = 128; off > 0; off >>= 1) {
        if (t < off) s[t] += s[t + off];
        __syncthreads();
    }
    if (t == 0) bsum[blk] = s[0];
}

// ---- 3) apply (each block rescans all 196 block sums locally) ----
__global__ __launch_bounds__(256) void scan_phase3(unsigned int* __restrict__ mat,
                                                   const unsigned int* __restrict__ bsum,
                                                   unsigned int* __restrict__ bstart) {
    __shared__ unsigned int s[256];
    __shared__ unsigned int bpre[256];
    const int blk = blockIdx.x, t = threadIdx.x;
    bpre[t] = (t < NB_SCAN) ? bsum[t] : 0u;
    __syncthreads();
    for (int off = 1; off < 256; off <<= 1) {
        unsigned int u = (t >= off) ? bpre[t - off] : 0u;
        __syncthreads();
        bpre[t] += u;
        __syncthreads();
    }
    const unsigned int blkbase = (blk == 0) ? 0u : bpre[blk - 1];

    const int base = blk * SCAN_CHUNK + t * 4;
    unsigned int c[4];
    unsigned int sum = 0;
#pragma unroll
    for (int k = 0; k < 4; ++k) {
        int i = base + k;
        c[k] = (i < MAT) ? mat[i] : 0u;
        sum += c[k];
    }
    s[t] = sum;
    __syncthreads();
    for (int off = 1; off < 256; off <<= 1) {
        unsigned int u = (t >= off) ? s[t - off] : 0u;
        __syncthreads();
        s[t] += u;
        __syncthreads();
    }
    unsigned int prefix = blkbase + ((t == 0) ? 0u : s[t - 1]);
#pragma unroll
    for (int k = 0; k < 4; ++k) {
        int i = base + k;
        if (i < MAT) {
            mat[i] = prefix;
            if ((i & (NWG - 1)) == 0) bstart[i >> 8] = prefix;
            prefix += c[k];
        }
    }
    if (blk == 0 && t == 0) bstart[NBUCKETS] = N_EDGES;
}

// ---- 4) placement (1024 thr): LDS cursors; int2 with pre-packed edge word ----
__global__ __launch_bounds__(1024) void place_kernel(const int* __restrict__ rows,
                                                     const int* __restrict__ cols,
                                                     const float* __restrict__ vals,
                                                     const unsigned int* __restrict__ mat,
                                                     int2* __restrict__ buf1) {
    __shared__ unsigned int lc[NBUCKETS];
    const int w = blockIdx.x, t = threadIdx.x;
    for (int b = t; b < NBUCKETS; b += 1024) lc[b] = mat[b * NWG + w];
    __syncthreads();
    const int lo = w * CHUNK;
    const int hi = (lo + CHUNK < N_EDGES) ? lo + CHUNK : N_EDGES;
    for (int e = lo + t; e < hi; e += 1024) {
        unsigned r = (unsigned)rows[e];
        unsigned c = (unsigned)cols[e];
        unsigned int pos = atomicAdd(&lc[r >> 7], 1u);   // LDS atomic only
        // val >= 0 -> fp16 RN bits fit in 15 bits (sign 0)
        unsigned hv = (unsigned)__half_as_ushort(__float2half_rn(vals[e]));
        buf1[pos] = make_int2((int)(((r & 127u) << 17) | c),
                              (int)((hv << 17) | c));
    }
}

// ---- 5) finalize: single-read register-cached sort + row-parallel spmm ----
__global__ __launch_bounds__(512) void finalize_spmm(const unsigned int* __restrict__ bstart,
                                                     const int2* __restrict__ buf1,
                                                     const __half2* __restrict__ embeds_h2,
                                                     float* __restrict__ out) {
    __shared__ unsigned int sedge[CAP];          // (fp16val<<17)|col, row-sorted
    __shared__ unsigned int rstart[RPB + 1];
    __shared__ unsigned int rc[RPB];
    __shared__ unsigned int wtot[2];
    const int b = blockIdx.x, t = threadIdx.x;
    const unsigned int S = bstart[b];
    const unsigned int E = bstart[b + 1];
    const unsigned int cnt = E - S;
    const int g   = t >> 5;        // 0..15: 16 groups, 8 rows each
    const int sub = t & 31;        // feature pair; active sub < 24
    const bool act = sub < 24;
    const int row0 = b * RPB;

#define PROC(q)                                                       \
    {                                                                 \
        union { __half h; unsigned short u; } hv;                     \
        hv.u = (unsigned short)((q) >> 17);                           \
        float vv = __half2float(hv.h);                                \
        __half2 e2v = embeds_h2[((q) & 0x1FFFFu) * 24 + sub];         \
        ax = fmaf(vv, __low2float(e2v), ax);                          \
        ay = fmaf(vv, __high2float(e2v), ay);                         \
    }

    if (t < RPB) rc[t] = 0u;
    __syncthreads();

    // pass 1 + register cache: each thread owns <=6 strided elements
    int2 c0, c1, c2, c3, c4, c5;
    if (cnt <= CAP) {
        unsigned int k = S + t;
#define STEP(ci)                                                      \
        if (k < E) {                                                  \
            ci = buf1[k];                                             \
            atomicAdd(&rc[(unsigned)ci.x >> 17], 1u);                 \
            k += 512;                                                 \
        }
        STEP(c0) STEP(c1) STEP(c2) STEP(c3) STEP(c4) STEP(c5)
#undef STEP
    }
    __syncthreads();
    // 2-wave shfl inclusive scan over 128 counts
    unsigned int myc = 0, inc = 0;
    if (t < RPB) {
        myc = rc[t];
        inc = myc;
#pragma unroll
        for (int off = 1; off < 64; off <<= 1) {
            unsigned int u = __shfl_up(inc, off, 64);
            if ((t & 63) >= off) inc += u;
        }
        if ((t & 63) == 63) wtot[t >> 6] = inc;
    }
    __syncthreads();
    if (t < RPB) {
        if (t >= 64) inc += wtot[0];
        unsigned int pre = inc - myc;
        rstart[t] = pre;
        rc[t] = pre;                       // reuse as scatter cursor
    }
    if (t == 0) rstart[RPB] = cnt;
    __syncthreads();

    if (cnt <= CAP) {
        // pass 2: scatter from REGISTERS into row-sorted LDS (no global re-read)
        {
            unsigned int k = S + t;
#define SCAT(ci)                                                      \
            if (k < E) {                                              \
                unsigned int pos = atomicAdd(&rc[(unsigned)ci.x >> 17], 1u); \
                sedge[pos] = (unsigned int)ci.y;                      \
                k += 512;                                             \
            }
            SCAT(c0) SCAT(c1) SCAT(c2) SCAT(c3) SCAT(c4) SCAT(c5)
#undef SCAT
        }
        __syncthreads();

        for (int rr = g * 8; rr < g * 8 + 8; ++rr) {
            int row = row0 + rr;
            if (row >= N_NODES) break;
            unsigned int j = rstart[rr], end = rstart[rr + 1];
            float ax = 0.f, ay = 0.f;
            for (; j + 8 <= end; j += 8) {
                unsigned int q0 = sedge[j + 0];
                unsigned int q1 = sedge[j + 1];
                unsigned int q2 = sedge[j + 2];
                unsigned int q3 = sedge[j + 3];
                unsigned int q4 = sedge[j + 4];
                unsigned int q5 = sedge[j + 5];
                unsigned int q6 = sedge[j + 6];
                unsigned int q7 = sedge[j + 7];
                if (act) {
                    PROC(q0) PROC(q1) PROC(q2) PROC(q3)
                    PROC(q4) PROC(q5) PROC(q6) PROC(q7)
                }
            }
            for (; j < end; ++j) {
                unsigned int q = sedge[j];
                if (act) PROC(q)
            }
            if (act)
                *(float2*)(out + (size_t)row * D_FEAT + sub * 2) = make_float2(ax, ay);
        }
    } else {
        // capacity-overflow fallback (~23-sigma event): filter-scan the window
        for (int rr = g * 8; rr < g * 8 + 8; ++rr) {
            int row = row0 + rr;
            if (row >= N_NODES) break;
            float ax = 0.f, ay = 0.f;
            for (unsigned int k = S; k < E; ++k) {
                int2 cv = buf1[k];
                if (((unsigned)cv.x >> 17) == (unsigned)rr && act) {
                    unsigned int q = (unsigned int)cv.y;
                    PROC(q)
                }
            }
            if (act)
                *(float2*)(out + (size_t)row * D_FEAT + sub * 2) = make_float2(ax, ay);
        }
    }
#undef PROC
}

// ---- fallback (tiny ws): edge-parallel global atomics ----
__global__ __launch_bounds__(256) void zero_out_kernel(float4* __restrict__ out, int n4) {
    int i = blockIdx.x * 256 + threadIdx.x;
    if (i < n4) out[i] = make_float4(0.f, 0.f, 0.f, 0.f);
}
__global__ __launch_bounds__(256) void spmm_atomic_kernel(const int* __restrict__ rows,
                                                          const int* __restrict__ cols,
                                                          const float* __restrict__ vals,
                                                          const float* __restrict__ embeds,
                                                          float* __restrict__ out) {
    long long tid = (long long)blockIdx.x * 256 + threadIdx.x;
    const long long total = (long long)N_EDGES * 12;
    if (tid >= total) return;
    int e = (int)(tid / 12), q = (int)(tid % 12);
    int r = rows[e], c = cols[e];
    float v = vals[e];
    const float4 emb = *(const float4*)(embeds + (long long)c * D_FEAT + q * 4);
    float* o = out + (long long)r * D_FEAT + q * 4;
    atomicAdd(o + 0, v * emb.x);
    atomicAdd(o + 1, v * emb.y);
    atomicAdd(o + 2, v * emb.z);
    atomicAdd(o + 3, v * emb.w);
}

extern "C" void kernel_launch(void* const* d_in, const int* in_sizes, int n_in,
                              void* d_out, int out_size, void* d_ws, size_t ws_size,
                              hipStream_t stream) {
    const int*   rows   = (const int*)d_in[0];
    const int*   cols   = (const int*)d_in[1];
    const float* vals   = (const float*)d_in[2];
    const float* embeds = (const float*)d_in[3];
    float*       out    = (float*)d_out;

    // workspace layout (~23.2 MB):
    //   mat: MAT u32 | bstart: NBUCKETS+1 | bsum: NB_SCAN | buf1: E int2 |
    //   embeds_h: N*48 fp16
    unsigned int* mat = (unsigned int*)d_ws;
    size_t mat_bytes  = ((size_t)MAT * 4 + 15) & ~(size_t)15;
    unsigned int* bstart = (unsigned int*)((char*)d_ws + mat_bytes);
    size_t bs_bytes   = (((size_t)(NBUCKETS + 1) * 4) + 15) & ~(size_t)15;
    unsigned int* bsum = (unsigned int*)((char*)d_ws + mat_bytes + bs_bytes);
    size_t bsum_bytes = (((size_t)NB_SCAN * 4) + 15) & ~(size_t)15;
    int2* buf1 = (int2*)((char*)d_ws + mat_bytes + bs_bytes + bsum_bytes);
    __half2* embeds_h2 = (__half2*)((char*)buf1 + (size_t)N_EDGES * 8);
    size_t need = mat_bytes + bs_bytes + bsum_bytes +
                  (size_t)N_EDGES * 8 + (size_t)N_NODES * D_FEAT * 2;

    if (ws_size < need) {
        int n4 = out_size / 4;
        zero_out_kernel<<<(n4 + 255) / 256, 256, 0, stream>>>((float4*)out, n4);
        long long total = (long long)N_EDGES * 12;
        spmm_atomic_kernel<<<(int)((total + 255) / 256), 256, 0, stream>>>(rows, cols, vals, embeds, out);
        return;
    }

    count_convert<<<NWG + CONV_BLK, 1024, 0, stream>>>(rows, mat,
                                                       (const float4*)embeds, embeds_h2);
    scan_phase1<<<NB_SCAN, 256, 0, stream>>>(mat, bsum);
    scan_phase3<<<NB_SCAN, 256, 0, stream>>>(mat, bsum, bstart);
    place_kernel<<<NWG, 1024, 0, stream>>>(rows, cols, vals, mat, buf1);
    finalize_spmm<<<NBUCKETS, 512, 0, stream>>>(bstart, buf1, embeds_h2, out);
}